// Round 8
// baseline (1323.925 us; speedup 1.0000x reference)
//
#include <hip/hip_runtime.h>

// SVSAlgorithm: per-pixel sequential threshold recurrence over T frames,
// fused with 3x3 constant-kernel "DiffErosion" conv + relu epilogue.
//
// Single-launch producer/consumer (retry of R5 with the spill fixed):
//  - blocks [0, 80): scan role, 256 thr, 1 chain/thread, R2-proven 2x32
//    double-buffered prefetch (64 data VGPRs live). Snapshot (HT,LT) every
//    SNAP=64 frames -> d_ws, then per-thread threadfence + block barrier +
//    one atomicAdd on flags[k]. Dispatched FIRST so producers are resident.
//  - blocks [80, 3920): compute role, slice-major (slice = cb/120) so the
//    earliest-resident compute blocks need the earliest snapshots; XCD
//    chunking within a slice (120 = 8*15, bijective) for output-line L2
//    merging. Slice 0 starts immediately; slice k>0 spins (thread 0,
//    s_sleep, 2ms realtime timeout) on flags[k-1]==80, falling back to a
//    bit-exact self-warm-up -> correct under ANY dispatch order.
//  - R5's failure root-caused: default __launch_bounds__(256) let the
//    allocator target 8 waves/SIMD (60 VGPR) and spill the scan arrays to
//    scratch. __launch_bounds__(256, 2) sets the target to 2 waves/SIMD ->
//    no spill (natural ~85 VGPR -> ~6 blocks/CU).
//  - compute: sigmoid via exp2(fma)+v_rcp; conv == box-sum (all 9 weights
//    equal): vertical = 2 LDS reads + own reg, horizontal via DPP
//    row_shr/row_shl; LDS sm[row][frame][col] (row stride 136 == 8 mod 32
//    banks -> <=2-way). State updates replicate reference f32 op order.
//  ws ladder: merged (5.1MB) -> split SNAP=128 (2.4MB) -> fused.

#define TILE_W 16
#define TILE_H 16
#define IN_W 14
#define IN_H 14
#define BUF 8        // frames per LDS stage in compute role
#define PRE 32       // scan prefetch half-depth (double buffer)

constexpr int T_FRAMES = 2048;
constexpr int H_IMG = 128;
constexpr int W_IMG = 160;
constexpr int HW = H_IMG * W_IMG;
constexpr int SNAP = 64;
constexpr int NSLICE = T_FRAMES / SNAP;          // 32
constexpr int NSNAP = NSLICE - 1;                // 31
constexpr int SCAN_BLOCKS = HW / 256;            // 80
constexpr int NTILE = 120;
constexpr int COMPUTE_BLOCKS = NTILE * NSLICE;   // 3840
constexpr size_t FLAGS_BYTES = 128;
constexpr size_t WS_MERGED = FLAGS_BYTES + (size_t)NSNAP * HW * sizeof(float2);
constexpr size_t WS_SPLIT128 = (size_t)(T_FRAMES / 128 - 1) * HW * sizeof(float2);
constexpr float C1 = 721.3475204444817f;         // 500 * log2(e)
constexpr unsigned long long SPIN_TIMEOUT = 200000ull;  // ~2ms @100MHz realtime

__device__ __forceinline__ float dpp_from_left(float v) {   // lane n <- lane n-1 (16-lane rows)
    return __int_as_float(__builtin_amdgcn_update_dpp(0, __float_as_int(v), 0x111, 0xF, 0xF, true));
}
__device__ __forceinline__ float dpp_from_right(float v) {  // lane n <- lane n+1
    return __int_as_float(__builtin_amdgcn_update_dpp(0, __float_as_int(v), 0x101, 0xF, 0xF, true));
}

__global__ __launch_bounds__(256, 2)
void svs_mono(const float* __restrict__ x, const float* __restrict__ params,
              const float* __restrict__ HT0, const float* __restrict__ LT0,
              const float* __restrict__ kern,
              float2* __restrict__ snap, int* __restrict__ flags,
              float* __restrict__ out)
{
    const float dC = params[0];
    const float dO = params[1];

    if (blockIdx.x < SCAN_BLOCKS) {
        // ---------------- scan role (R2-proven 2x32 double buffer) --------
        const int pix = (int)blockIdx.x * 256 + (int)threadIdx.x;
        float HT = HT0[pix];
        float LT = LT0[pix];
        const float* xp = x + pix;

        float va[PRE], vb[PRE];
        #pragma unroll
        for (int i = 0; i < PRE; ++i) va[i] = xp[i * HW];

        // frames beyond 1983 are not needed by any consumer (last snapshot
        // k=30 = state after frame 1983)
        for (int t = 0; t < T_FRAMES - SNAP; t += 2 * PRE) {
            #pragma unroll
            for (int i = 0; i < PRE; ++i) vb[i] = xp[(t + PRE + i) * HW];
            #pragma unroll
            for (int i = 0; i < PRE; ++i) {
                const float img = va[i];
                HT = ((img - HT) > 0.0f) ? (HT + dO) : (HT - dC);
                LT = ((LT - img) > 0.0f) ? (LT - dO) : (LT + dC);
            }
            const bool more = (t + 2 * PRE) < (T_FRAMES - SNAP);
            if (more) {
                #pragma unroll
                for (int i = 0; i < PRE; ++i) va[i] = xp[(t + 2 * PRE + i) * HW];
            }
            #pragma unroll
            for (int i = 0; i < PRE; ++i) {
                const float img = vb[i];
                HT = ((img - HT) > 0.0f) ? (HT + dO) : (HT - dC);
                LT = ((LT - img) > 0.0f) ? (LT - dO) : (LT + dC);
            }
            // state now at frame t+63; snapshot k = t/64 (k < 31 always here)
            const int k = t / SNAP;
            snap[(size_t)k * HW + pix] = make_float2(HT, LT);
            __threadfence();                       // push this thread's store
            __syncthreads();                       // all block stores pushed
            if (threadIdx.x == 0)
                __atomic_fetch_add(&flags[k], 1, __ATOMIC_RELAXED);
        }
        return;
    }

    // ---------------- compute role ----------------
    const int cb = (int)blockIdx.x - SCAN_BLOCKS;
    const int slice = cb / NTILE;                 // slice-major: early blocks
    const int c  = cb % NTILE;                    // need early snapshots
    const int w  = (c & 7) * 15 + (c >> 3);       // XCD chunk within slice
    const int bx = w % 12;
    const int by = w / 12;

    const int tx = threadIdx.x & 15;
    const int ty = threadIdx.x >> 4;
    const int gx = bx * IN_W + tx - 1;
    const int gy = by * IN_H + ty - 1;
    const int t0 = slice * SNAP;

    const bool valid = (gx >= 0) & (gx < W_IMG) & (gy >= 0) & (gy < H_IMG);
    const int cx = min(max(gx, 0), W_IMG - 1);
    const int cy = min(max(gy, 0), H_IMG - 1);
    const int pix = cy * W_IMG + cx;

    const float dHot = params[2];
    const float kw   = kern[4];        // all 9 weights equal (2/9)
    const float c0   = dHot * C1;      // exp2 arg = fma(a, -C1, c0)
    const float* xp  = x + pix;
    float* op = out + pix;

    // sm[row][frame][col]: row stride 136 floats == 8 mod 32 banks ->
    // wave's 4 row-clusters at bank shifts {0,8,16,24}: <=2-way (free).
    __shared__ float sm[TILE_H][BUF][TILE_W + 1];
    __shared__ int sReady;

    float HT, LT;
    if (slice == 0) {
        HT = valid ? HT0[pix] : 0.0f;
        LT = valid ? LT0[pix] : 0.0f;
    } else {
        if (threadIdx.x == 0) {
            int got = __atomic_load_n(&flags[slice - 1], __ATOMIC_RELAXED);
            if (got < SCAN_BLOCKS) {
                const unsigned long long ts = __builtin_amdgcn_s_memrealtime();
                do {
                    __builtin_amdgcn_s_sleep(32);
                    got = __atomic_load_n(&flags[slice - 1], __ATOMIC_RELAXED);
                } while (got < SCAN_BLOCKS &&
                         (__builtin_amdgcn_s_memrealtime() - ts) < SPIN_TIMEOUT);
            }
            sReady = (got >= SCAN_BLOCKS) ? 1 : 0;
        }
        __syncthreads();
        if (sReady) {
            __threadfence();                      // acquire side
            const float2 s = snap[(size_t)(slice - 1) * HW + pix];
            HT = valid ? s.x : 0.0f;
            LT = valid ? s.y : 0.0f;
        } else {
            // timeout fallback: bit-exact self-warm-up (identical f32 chain)
            HT = valid ? HT0[pix] : 0.0f;
            LT = valid ? LT0[pix] : 0.0f;
            for (int t = 0; t < t0; t += 8) {
                float v[8];
                #pragma unroll
                for (int i = 0; i < 8; ++i) v[i] = xp[(t + i) * HW];
                #pragma unroll
                for (int i = 0; i < 8; ++i) {
                    const float img = v[i];
                    HT = ((img - HT) > 0.0f) ? (HT + dO) : (HT - dC);
                    LT = ((LT - img) > 0.0f) ? (LT - dO) : (LT + dC);
                }
            }
        }
    }

    const bool doOut = (tx >= 1) & (tx <= IN_W) & (ty >= 1) & (ty <= IN_H) & valid;
    const int ym = max(ty - 1, 0);
    const int yp = min(ty + 1, TILE_H - 1);

    for (int tb = t0; tb < t0 + SNAP; tb += BUF) {
        float v[BUF], hot[BUF];
        #pragma unroll
        for (int i = 0; i < BUF; ++i) v[i] = xp[(tb + i) * HW];
        #pragma unroll
        for (int i = 0; i < BUF; ++i) {
            const float img = v[i];
            const float aH = img - HT;
            const float eH = __builtin_amdgcn_exp2f(fmaf(aH, -C1, c0));
            const float hH = __builtin_amdgcn_rcpf(1.0f + eH);
            HT = (aH > 0.0f) ? (HT + dO) : (HT - dC);
            const float aL = LT - img;
            const float eL = __builtin_amdgcn_exp2f(fmaf(aL, -C1, c0));
            const float hL = __builtin_amdgcn_rcpf(1.0f + eL);
            LT = (aL > 0.0f) ? (LT - dO) : (LT + dC);
            hot[i] = valid ? (hH + hL) : 1.0f;
            sm[ty][i][tx] = hot[i];
        }
        __syncthreads();
        #pragma unroll
        for (int i = 0; i < BUF; ++i) {
            const float r0 = sm[ym][i][tx];
            const float r1 = sm[yp][i][tx];
            const float vs = r0 + hot[i] + r1;               // vertical box sum
            const float S  = vs + dpp_from_left(vs) + dpp_from_right(vs);
            float o = fmaf(S, kw, -1.0f);                    // 1 - kw*(9-S) = kw*S - 1
            o = fmaxf(o, 0.0f);
            if (doOut) op[(tb + i) * HW] = o;
        }
        __syncthreads();
    }
}

// ---------------- Split fallbacks (ws too small for merged) ---------------
__global__ __launch_bounds__(256)
void svs_scan128(const float* __restrict__ x, const float* __restrict__ params,
                 const float* __restrict__ HT0, const float* __restrict__ LT0,
                 float2* __restrict__ snap)
{
    const int pix = (int)blockIdx.x * 256 + (int)threadIdx.x;
    const float dC = params[0];
    const float dO = params[1];
    float HT = HT0[pix];
    float LT = LT0[pix];
    const float* xp = x + pix;

    float va[PRE], vb[PRE];
    #pragma unroll
    for (int i = 0; i < PRE; ++i) va[i] = xp[i * HW];

    for (int t = 0; t < T_FRAMES; t += 2 * PRE) {
        #pragma unroll
        for (int i = 0; i < PRE; ++i) vb[i] = xp[(t + PRE + i) * HW];
        #pragma unroll
        for (int i = 0; i < PRE; ++i) {
            const float img = va[i];
            HT = ((img - HT) > 0.0f) ? (HT + dO) : (HT - dC);
            LT = ((LT - img) > 0.0f) ? (LT - dO) : (LT + dC);
        }
        if (t + 2 * PRE < T_FRAMES) {
            #pragma unroll
            for (int i = 0; i < PRE; ++i) va[i] = xp[(t + 2 * PRE + i) * HW];
        }
        #pragma unroll
        for (int i = 0; i < PRE; ++i) {
            const float img = vb[i];
            HT = ((img - HT) > 0.0f) ? (HT + dO) : (HT - dC);
            LT = ((LT - img) > 0.0f) ? (LT - dO) : (LT + dC);
        }
        if (((t + 2 * PRE) & 127) == 0) {
            const int k = (t + 2 * PRE) / 128 - 1;
            if (k < T_FRAMES / 128 - 1) snap[(size_t)k * HW + pix] = make_float2(HT, LT);
        }
    }
}

template <int SNAP_>
__global__ __launch_bounds__(256)
void svs_compute(const float* __restrict__ x, const float* __restrict__ params,
                 const float* __restrict__ HT0, const float* __restrict__ LT0,
                 const float* __restrict__ kern, const float2* __restrict__ snap,
                 float* __restrict__ out)
{
    constexpr int TOTAL_ = 120 * (T_FRAMES / SNAP_);
    const int lin = (int)blockIdx.x + 12 * (int)blockIdx.y + 120 * (int)blockIdx.z;
    const int w   = (lin & 7) * (TOTAL_ / 8) + (lin >> 3);
    const int bx  = w % 12;
    const int by  = (w / 12) % 10;
    const int slice = w / 120;

    const int tx = threadIdx.x & 15;
    const int ty = threadIdx.x >> 4;
    const int gx = bx * IN_W + tx - 1;
    const int gy = by * IN_H + ty - 1;
    const int t0 = slice * SNAP_;

    const bool valid = (gx >= 0) & (gx < W_IMG) & (gy >= 0) & (gy < H_IMG);
    const int cx = min(max(gx, 0), W_IMG - 1);
    const int cy = min(max(gy, 0), H_IMG - 1);
    const int pix = cy * W_IMG + cx;

    const float dC   = params[0];
    const float dO   = params[1];
    const float dHot = params[2];
    const float kw   = kern[4];
    const float c0   = dHot * C1;

    float HT, LT;
    if (slice == 0) {
        HT = valid ? HT0[pix] : 0.0f;
        LT = valid ? LT0[pix] : 0.0f;
    } else {
        const float2 s = snap[(size_t)(slice - 1) * HW + pix];
        HT = valid ? s.x : 0.0f;
        LT = valid ? s.y : 0.0f;
    }

    __shared__ float sm[TILE_H][BUF][TILE_W + 1];
    const bool doOut = (tx >= 1) & (tx <= IN_W) & (ty >= 1) & (ty <= IN_H) & valid;
    const int ym = max(ty - 1, 0);
    const int yp = min(ty + 1, TILE_H - 1);
    const float* xp = x + pix;
    float* op = out + pix;

    for (int tb = t0; tb < t0 + SNAP_; tb += BUF) {
        float v[BUF], hot[BUF];
        #pragma unroll
        for (int i = 0; i < BUF; ++i) v[i] = xp[(tb + i) * HW];
        #pragma unroll
        for (int i = 0; i < BUF; ++i) {
            const float img = v[i];
            const float aH = img - HT;
            const float eH = __builtin_amdgcn_exp2f(fmaf(aH, -C1, c0));
            const float hH = __builtin_amdgcn_rcpf(1.0f + eH);
            HT = (aH > 0.0f) ? (HT + dO) : (HT - dC);
            const float aL = LT - img;
            const float eL = __builtin_amdgcn_exp2f(fmaf(aL, -C1, c0));
            const float hL = __builtin_amdgcn_rcpf(1.0f + eL);
            LT = (aL > 0.0f) ? (LT - dO) : (LT + dC);
            hot[i] = valid ? (hH + hL) : 1.0f;
            sm[ty][i][tx] = hot[i];
        }
        __syncthreads();
        #pragma unroll
        for (int i = 0; i < BUF; ++i) {
            const float r0 = sm[ym][i][tx];
            const float r1 = sm[yp][i][tx];
            const float vs = r0 + hot[i] + r1;
            const float S  = vs + dpp_from_left(vs) + dpp_from_right(vs);
            float o = fmaf(S, kw, -1.0f);
            o = fmaxf(o, 0.0f);
            if (doOut) op[(tb + i) * HW] = o;
        }
        __syncthreads();
    }
}

extern "C" void kernel_launch(void* const* d_in, const int* in_sizes, int n_in,
                              void* d_out, int out_size, void* d_ws, size_t ws_size,
                              hipStream_t stream) {
    const float* x      = (const float*)d_in[0];
    const float* params = (const float*)d_in[1];
    const float* HT0p   = (const float*)d_in[2];
    const float* LT0p   = (const float*)d_in[3];
    const float* kern   = (const float*)d_in[4];
    float* out = (float*)d_out;

    if (ws_size >= WS_MERGED) {
        int* flags = (int*)d_ws;
        float2* snap = (float2*)((char*)d_ws + FLAGS_BYTES);
        (void)hipMemsetAsync(d_ws, 0, FLAGS_BYTES, stream);
        svs_mono<<<dim3(SCAN_BLOCKS + COMPUTE_BLOCKS), dim3(256), 0, stream>>>(
            x, params, HT0p, LT0p, kern, snap, flags, out);
    } else if (ws_size >= WS_SPLIT128) {
        float2* snap = (float2*)d_ws;
        svs_scan128<<<dim3(HW / 256), dim3(256), 0, stream>>>(x, params, HT0p, LT0p, snap);
        svs_compute<128><<<dim3(12, 10, T_FRAMES / 128), dim3(256), 0, stream>>>(
            x, params, HT0p, LT0p, kern, snap, out);
    } else {
        // minimal safety net: recompute-from-0 fused (slow but correct)
        svs_compute<2048><<<dim3(12, 10, 1), dim3(256), 0, stream>>>(
            x, params, HT0p, LT0p, kern, (const float2*)d_ws, out);
    }
}

// Round 9
// 145.937 us; speedup vs baseline: 9.0719x; 9.0719x over previous
//
#include <hip/hip_runtime.h>

// SVSAlgorithm: per-pixel sequential threshold recurrence over T frames,
// fused with 3x3 constant-kernel "DiffErosion" conv + relu epilogue.
//
// Two-launch design (merged producer/consumer abandoned: R5+R8 both showed
// the compiler sinks the scan's prefetch loads to fit one shared register
// budget, collapsing the pipeline):
//  L1 svs_scan<SNAP>: 80 blocks x 256 thr, 1 chain/thread. TRIPLE-buffered
//     PRE=32 prefetch -> ~63 outstanding loads/wave (vmcnt cap) ~ 5.2MB in
//     flight device-wide ~ BW*latency, vs double-buffer's 2.6MB (2.8 TB/s).
//     Each issue block is pinned with sched_barrier(0) so the scheduler
//     cannot sink loads to their uses (the R6/R7 collapse mechanism).
//     __launch_bounds__(256,1): ~112 VGPR fits; only 80/256 CUs run scan so
//     occupancy is irrelevant. Skips frames >= TEFF (never consumed).
//     Snapshots (HT,LT) every SNAP frames -> d_ws.
//  L2 svs_compute<SNAP>: proven R6 kernel verbatim. 16x16 tile (14x14
//     interior + halo recompute), one block per (tile, SNAP-frame slice);
//     SNAP=64 -> 3840 blocks. Sigmoid via exp2(fma)+v_rcp; conv == box-sum
//     (all 9 weights equal): vertical = 2 LDS reads + own reg, horizontal
//     via DPP row_shr/row_shl; LDS sm[row][frame][col] (row stride 136 ==
//     8 mod 32 banks -> <=2-way). XCD-grouped block remap for output-line
//     L2 merging. State updates replicate reference f32 op order exactly.
//  ws ladder: SNAP=64 (5.1MB) -> SNAP=128 (2.4MB) -> single-slice compute.

#define TILE_W 16
#define TILE_H 16
#define IN_W 14
#define IN_H 14
#define BUF 8        // frames per LDS stage in compute pass
#define PRE 32       // scan batch size (3 buffers)

constexpr int T_FRAMES = 2048;
constexpr int H_IMG = 128;
constexpr int W_IMG = 160;
constexpr int HW = H_IMG * W_IMG;
constexpr float C1 = 721.3475204444817f;         // 500 * log2(e)

constexpr size_t ws_needed(int snap) {
    return (size_t)(T_FRAMES / snap - 1) * HW * sizeof(float2);
}

__device__ __forceinline__ float dpp_from_left(float v) {   // lane n <- lane n-1 (16-lane rows)
    return __int_as_float(__builtin_amdgcn_update_dpp(0, __float_as_int(v), 0x111, 0xF, 0xF, true));
}
__device__ __forceinline__ float dpp_from_right(float v) {  // lane n <- lane n+1
    return __int_as_float(__builtin_amdgcn_update_dpp(0, __float_as_int(v), 0x101, 0xF, 0xF, true));
}

// ---------------- L1: state-only scan, triple-buffered prefetch -----------
#define S_ISSUE(V, F)                              \
    _Pragma("unroll")                              \
    for (int i = 0; i < PRE; ++i) V[i] = xp[((F) + i) * HW];

#define S_COMP(V)                                  \
    _Pragma("unroll")                              \
    for (int i = 0; i < PRE; ++i) {                \
        const float img = V[i];                    \
        HT = ((img - HT) > 0.0f) ? (HT + dO) : (HT - dC); \
        LT = ((LT - img) > 0.0f) ? (LT - dO) : (LT + dC); \
    }

template <int SNAP_>
__global__ __launch_bounds__(256, 1)
void svs_scan(const float* __restrict__ x, const float* __restrict__ params,
              const float* __restrict__ HT0, const float* __restrict__ LT0,
              float2* __restrict__ snap)
{
    // frames >= TEFF are never consumed (last snapshot = state after TEFF-1)
    constexpr int TEFF = T_FRAMES - SNAP_;
    const int pix = (int)blockIdx.x * 256 + (int)threadIdx.x;  // 80 blocks
    const float dC = params[0];
    const float dO = params[1];

    float HT = HT0[pix];
    float LT = LT0[pix];
    const float* xp = x + pix;

    auto maybe_snap = [&](int endf) {
        if ((endf % SNAP_) == 0) {
            const int k = endf / SNAP_ - 1;
            if (k < T_FRAMES / SNAP_ - 1)
                snap[(size_t)k * HW + pix] = make_float2(HT, LT);
        }
    };

    float va[PRE], vb[PRE], vc[PRE];
    S_ISSUE(va, 0)
    S_ISSUE(vb, PRE)
    __builtin_amdgcn_sched_barrier(0);

    for (int t = 0; t < TEFF; t += 3 * PRE) {
        if (t + 2 * PRE < TEFF) { S_ISSUE(vc, t + 2 * PRE) }
        __builtin_amdgcn_sched_barrier(0);
        S_COMP(va)
        maybe_snap(t + PRE);
        if (t + 3 * PRE < TEFF) { S_ISSUE(va, t + 3 * PRE) }
        __builtin_amdgcn_sched_barrier(0);
        if (t + PRE < TEFF) {
            S_COMP(vb)
            maybe_snap(t + 2 * PRE);
        }
        if (t + 4 * PRE < TEFF) { S_ISSUE(vb, t + 4 * PRE) }
        __builtin_amdgcn_sched_barrier(0);
        if (t + 2 * PRE < TEFF) {
            S_COMP(vc)
            maybe_snap(t + 3 * PRE);
        }
    }
}

// ---------------- L2: per-slice fused compute (proven R6 kernel) ----------
template <int SNAP_>
__global__ __launch_bounds__(256)
void svs_compute(const float* __restrict__ x, const float* __restrict__ params,
                 const float* __restrict__ HT0, const float* __restrict__ LT0,
                 const float* __restrict__ kern, const float2* __restrict__ snap,
                 float* __restrict__ out)
{
    constexpr int NSLICE_ = T_FRAMES / SNAP_;
    constexpr int TOTAL_ = 120 * NSLICE_;
    // XCD-grouped remap: contiguous chunks of linear block id per XCD so
    // adjacent-bx tiles (sharing output cache lines) land on one XCD L2.
    const int lin = (int)blockIdx.x + 12 * (int)blockIdx.y + 120 * (int)blockIdx.z;
    const int w   = (lin & 7) * (TOTAL_ / 8) + (lin >> 3);   // TOTAL_%8==0 -> bijective
    const int bx  = w % 12;
    const int by  = (w / 12) % 10;
    const int slice = w / 120;

    const int tx = threadIdx.x & 15;
    const int ty = threadIdx.x >> 4;
    const int gx = bx * IN_W + tx - 1;
    const int gy = by * IN_H + ty - 1;
    const int t0 = slice * SNAP_;

    const bool valid = (gx >= 0) & (gx < W_IMG) & (gy >= 0) & (gy < H_IMG);
    const int cx = min(max(gx, 0), W_IMG - 1);
    const int cy = min(max(gy, 0), H_IMG - 1);
    const int pix = cy * W_IMG + cx;

    const float dC   = params[0];
    const float dO   = params[1];
    const float dHot = params[2];
    const float kw   = kern[4];        // all 9 weights equal (2/9)
    const float c0   = dHot * C1;      // exp2 arg = fma(a, -C1, c0)

    float HT, LT;
    if (slice == 0) {
        HT = valid ? HT0[pix] : 0.0f;
        LT = valid ? LT0[pix] : 0.0f;
    } else {
        const float2 s = snap[(size_t)(slice - 1) * HW + pix];
        HT = valid ? s.x : 0.0f;
        LT = valid ? s.y : 0.0f;
    }

    // sm[row][frame][col]: row stride 136 floats == 8 mod 32 banks ->
    // wave's 4 row-clusters at bank shifts {0,8,16,24}: <=2-way (free).
    __shared__ float sm[TILE_H][BUF][TILE_W + 1];

    const bool doOut = (tx >= 1) & (tx <= IN_W) & (ty >= 1) & (ty <= IN_H) & valid;
    const int ym = max(ty - 1, 0);
    const int yp = min(ty + 1, TILE_H - 1);
    const float* xp = x + pix;
    float* op = out + pix;

    for (int tb = t0; tb < t0 + SNAP_; tb += BUF) {
        float v[BUF], hot[BUF];
        #pragma unroll
        for (int i = 0; i < BUF; ++i) v[i] = xp[(tb + i) * HW];
        #pragma unroll
        for (int i = 0; i < BUF; ++i) {
            const float img = v[i];
            const float aH = img - HT;
            const float eH = __builtin_amdgcn_exp2f(fmaf(aH, -C1, c0));
            const float hH = __builtin_amdgcn_rcpf(1.0f + eH);
            HT = (aH > 0.0f) ? (HT + dO) : (HT - dC);
            const float aL = LT - img;
            const float eL = __builtin_amdgcn_exp2f(fmaf(aL, -C1, c0));
            const float hL = __builtin_amdgcn_rcpf(1.0f + eL);
            LT = (aL > 0.0f) ? (LT - dO) : (LT + dC);
            hot[i] = valid ? (hH + hL) : 1.0f;
            sm[ty][i][tx] = hot[i];
        }
        __syncthreads();
        #pragma unroll
        for (int i = 0; i < BUF; ++i) {
            const float r0 = sm[ym][i][tx];
            const float r1 = sm[yp][i][tx];
            const float vs = r0 + hot[i] + r1;               // vertical box sum
            const float S  = vs + dpp_from_left(vs) + dpp_from_right(vs);
            float o = fmaf(S, kw, -1.0f);                    // 1 - kw*(9-S) = kw*S - 1
            o = fmaxf(o, 0.0f);
            if (doOut) op[(tb + i) * HW] = o;
        }
        __syncthreads();
    }
}

extern "C" void kernel_launch(void* const* d_in, const int* in_sizes, int n_in,
                              void* d_out, int out_size, void* d_ws, size_t ws_size,
                              hipStream_t stream) {
    const float* x      = (const float*)d_in[0];
    const float* params = (const float*)d_in[1];
    const float* HT0p   = (const float*)d_in[2];
    const float* LT0p   = (const float*)d_in[3];
    const float* kern   = (const float*)d_in[4];
    float* out = (float*)d_out;

    if (ws_size >= ws_needed(64)) {
        float2* snap = (float2*)d_ws;
        svs_scan<64><<<dim3(HW / 256), dim3(256), 0, stream>>>(x, params, HT0p, LT0p, snap);
        svs_compute<64><<<dim3(12, 10, T_FRAMES / 64), dim3(256), 0, stream>>>(
            x, params, HT0p, LT0p, kern, snap, out);
    } else if (ws_size >= ws_needed(128)) {
        float2* snap = (float2*)d_ws;
        svs_scan<128><<<dim3(HW / 256), dim3(256), 0, stream>>>(x, params, HT0p, LT0p, snap);
        svs_compute<128><<<dim3(12, 10, T_FRAMES / 128), dim3(256), 0, stream>>>(
            x, params, HT0p, LT0p, kern, snap, out);
    } else {
        // safety net: single-slice recompute-from-0 (snap never read)
        svs_compute<2048><<<dim3(12, 10, 1), dim3(256), 0, stream>>>(
            x, params, HT0p, LT0p, kern, (const float2*)d_ws, out);
    }
}